// Round 12
// baseline (28.361 us; speedup 1.0000x reference)
//
#include <hip/hip_runtime.h>

#define BB 16
#define NN 2048
#define NFF 512
#define DD 4
#define BN (BB * NN)   // 32768

#define ROWS 64        // K-rows per gemv block (lane l <-> row l)
#define WR 16          // rows per wave in the compute loop
#define YINT 32        // 32*64 = 2048 Wint rows
#define YTOT 40        // + 8*64 = 512 Wff rows
#define JC   256       // columns per x-block (64 lanes x 4 cols, float4)
#define NX   (NN / JC) // 8 column groups

// ---------------- Kernel A: GEMV (R10 structure, unchanged) ----------------
__global__ __launch_bounds__(256) void snn_gemv(
    const float* __restrict__ Wint, const float* __restrict__ Wff,
    const float* __restrict__ Xbuf, const float* __restrict__ stp,
    const float* __restrict__ FF,
    const float* __restrict__ xpre_int, const float* __restrict__ xpre_ff,
    float* __restrict__ part, float* __restrict__ scal_part)
{
    __shared__ __align__(16) float c_lds[BB * ROWS];   // 4 KB  [b][row]
    __shared__ float4 red[2 * BB * 64];                // 32 KB [buf][b][lane]
    int x = blockIdx.x, y = blockIdx.y;
    int t = threadIdx.x;
    int w = t >> 6, l = t & 63;
    const float* Wm; int i0;

    if (y < YINT) {
        i0 = y * ROWS; Wm = Wint;
        #pragma unroll
        for (int bb = 0; bb < 4; ++bb) {
            int b = w * 4 + bb;
            int base = b * NN + i0 + l;
            float acc = 0.f;
            #pragma unroll
            for (int d = 0; d < DD; ++d) {
                float xd = Xbuf[d * BN + base];   // coalesced 256B
                float s  = stp[d * BN + base];
                acc += xd * (1.f + 0.95f * s - 0.3f * xd);
            }
            c_lds[b * ROWS + l] = acc;            // lane-consecutive write
        }
    } else {
        i0 = (y - YINT) * ROWS; Wm = Wff;
        #pragma unroll
        for (int bb = 0; bb < 4; ++bb) {
            int b = w * 4 + bb;
            c_lds[b * ROWS + l] = FF[b * NFF + i0 + l];
        }
    }
    __syncthreads();

    // scal partials (x==0 blocks; all reads coalesced, wave-parallel)
    if (x == 0) {
        #pragma unroll
        for (int bb = 0; bb < 4; ++bb) {
            int b = w * 4 + bb;
            float tv = c_lds[b * ROWS + l];
            float s0, s1;
            if (y < YINT) {
                s0 = tv * xpre_int[b * NN + i0 + l];
                s1 = tv * Xbuf[b * NN + i0 + l];          // Xd0
            } else {
                s0 = tv * xpre_ff[b * NFF + i0 + l];
                s1 = tv * tv;
            }
            #pragma unroll
            for (int o = 32; o; o >>= 1) { s0 += __shfl_xor(s0, o); s1 += __shfl_xor(s1, o); }
            if (l == 0) {
                scal_part[y * 32 + b]      = s0;
                scal_part[y * 32 + 16 + b] = s1;
            }
        }
    }

    int j0 = x * JC + l * 4;

    // issue ALL 16 row loads up front (16 x 16B outstanding per lane)
    const float* wp = Wm + (size_t)(i0 + w * WR) * NN + j0;
    float4 buf[WR];
    #pragma unroll
    for (int r = 0; r < WR; ++r) buf[r] = *(const float4*)(wp + (size_t)r * NN);

    float4 acc[BB];
    #pragma unroll
    for (int b = 0; b < BB; ++b) acc[b] = make_float4(0.f, 0.f, 0.f, 0.f);

    // 4 rows per step; c_lds read is a float4 broadcast across rows
    #pragma unroll
    for (int rg = 0; rg < 4; ++rg) {
        float4 wv0 = buf[rg * 4 + 0], wv1 = buf[rg * 4 + 1];
        float4 wv2 = buf[rg * 4 + 2], wv3 = buf[rg * 4 + 3];
        int base = w * WR + rg * 4;
#define FMA16(b) { \
        float4 cr = *(const float4*)&c_lds[(b) * ROWS + base]; \
        acc[b].x += cr.x * wv0.x + cr.y * wv1.x + cr.z * wv2.x + cr.w * wv3.x; \
        acc[b].y += cr.x * wv0.y + cr.y * wv1.y + cr.z * wv2.y + cr.w * wv3.y; \
        acc[b].z += cr.x * wv0.z + cr.y * wv1.z + cr.z * wv2.z + cr.w * wv3.z; \
        acc[b].w += cr.x * wv0.w + cr.y * wv1.w + cr.z * wv2.w + cr.w * wv3.w; }
        FMA16(0)  FMA16(1)  FMA16(2)  FMA16(3)
        FMA16(4)  FMA16(5)  FMA16(6)  FMA16(7)
        FMA16(8)  FMA16(9)  FMA16(10) FMA16(11)
        FMA16(12) FMA16(13) FMA16(14) FMA16(15)
#undef FMA16
    }

    // tree-reduce 4 waves: [b][lane] float4, contiguous b128 ops
    if (w >= 2) {
        float4* rb = &red[(w - 2) * BB * 64];
        #pragma unroll
        for (int b = 0; b < BB; ++b) rb[b * 64 + l] = acc[b];
    }
    __syncthreads();
    if (w < 2) {
        const float4* rb = &red[w * BB * 64];
        #pragma unroll
        for (int b = 0; b < BB; ++b) {
            float4 v = rb[b * 64 + l];
            acc[b].x += v.x; acc[b].y += v.y; acc[b].z += v.z; acc[b].w += v.w;
        }
    }
    __syncthreads();
    if (w == 1) {
        #pragma unroll
        for (int b = 0; b < BB; ++b) red[b * 64 + l] = acc[b];
    }
    __syncthreads();
    if (w == 0) {
        float* pp = part + (size_t)y * BN + j0;
        #pragma unroll
        for (int b = 0; b < BB; ++b) {
            float4 v = red[b * 64 + l];
            acc[b].x += v.x; acc[b].y += v.y; acc[b].z += v.z; acc[b].w += v.w;
            *(float4*)(pp + (size_t)b * NN) = acc[b];
        }
    }
}

// ---------------- Kernel B: X + reduce partials + finalize ----------------
__global__ __launch_bounds__(256) void snn_post(
    const float* __restrict__ V, const float* __restrict__ th,
    const float* __restrict__ xpost,
    const float* __restrict__ part, const float* __restrict__ scal_part,
    float* __restrict__ out_X, float* __restrict__ out_V)
{
    int idx = blockIdx.x * 256 + threadIdx.x;
    int b = idx >> 11;                   // block-uniform
    float c1 = 0.f, c2 = 0.f, c3 = 0.f, c4 = 0.f;
    #pragma unroll
    for (int y = 0; y < YINT; ++y) {
        c1 += scal_part[y * 32 + b];
        c2 += scal_part[y * 32 + 16 + b];
    }
    #pragma unroll
    for (int y = YINT; y < YTOT; ++y) {
        c3 += scal_part[y * 32 + b];
        c4 += scal_part[y * 32 + 16 + b];
    }
    float v = V[idx];
    float x = 1.f / (1.f + expf(-(v - 1.f - th[idx]) * 5.f));
    out_X[idx] = x;
    float s = 0.f;
    #pragma unroll
    for (int y = 0; y < YTOT; ++y) s += part[(size_t)y * BN + idx];
    float c = s + 0.01f * (c1 + c3) * x - 0.012f * (c2 + c4) * xpost[idx];
    out_V[idx] = 0.9f * v * (1.f - x) + c;
}

extern "C" void kernel_launch(void* const* d_in, const int* in_sizes, int n_in,
                              void* d_out, int out_size, void* d_ws, size_t ws_size,
                              hipStream_t stream) {
    const float* FF       = (const float*)d_in[0];
    const float* V        = (const float*)d_in[1];
    const float* th       = (const float*)d_in[2];
    const float* Xbuf     = (const float*)d_in[3];
    const float* stp      = (const float*)d_in[4];
    const float* xpre_int = (const float*)d_in[5];
    const float* xpost    = (const float*)d_in[6];
    const float* xpre_ff  = (const float*)d_in[7];
    const float* Wint     = (const float*)d_in[8];
    const float* Wff      = (const float*)d_in[9];
    float* out = (float*)d_out;
    float* ws  = (float*)d_ws;

    float* part = ws;                    // 40 * 32768 floats (plain stores)
    float* sp   = ws + YTOT * BN;        // 1280 floats (plain stores)

    // ATTRIBUTION EXPERIMENT: run gemv twice (identical work, identical
    // output values -> deterministic, post reads the same totals). The
    // timed delta vs R10's 18.8us is gemv's true marginal (L3-warm) cost.
    snn_gemv<<<dim3(NX, YTOT), 256, 0, stream>>>(
        Wint, Wff, Xbuf, stp, FF, xpre_int, xpre_ff, part, sp);

    snn_gemv<<<dim3(NX, YTOT), 256, 0, stream>>>(
        Wint, Wff, Xbuf, stp, FF, xpre_int, xpre_ff, part, sp);

    snn_post<<<BN / 256, 256, 0, stream>>>(
        V, th, xpost, part, sp, out, out + BN);
}

// Round 13
// 19.323 us; speedup vs baseline: 1.4677x; 1.4677x over previous
//
#include <hip/hip_runtime.h>

#define BB 16
#define NN 2048
#define NFF 512
#define DD 4
#define BN (BB * NN)   // 32768

#define ROWS 64        // K-rows per gemv block (lane l <-> row l)
#define WR 16          // rows per wave in the compute loop
#define YINT 32        // 32*64 = 2048 Wint rows
#define YTOT 40        // + 8*64 = 512 Wff rows
#define JC   256       // columns per x-block (64 lanes x 4 cols, float4)
#define NX   (NN / JC) // 8 column groups

// ---------------- Kernel A: GEMV, register-pressure-capped ----------------
// part[y][b][j] = sum_{i in y's 64 rows} OP[b,i] * W[i,j]
// W-row loads split into two half-passes of 8 so peak live state is
// acc(64) + buf(32) + temps instead of acc(64) + buf(64) + temps.
__global__ __launch_bounds__(256) void snn_gemv(
    const float* __restrict__ Wint, const float* __restrict__ Wff,
    const float* __restrict__ Xbuf, const float* __restrict__ stp,
    const float* __restrict__ FF,
    const float* __restrict__ xpre_int, const float* __restrict__ xpre_ff,
    float* __restrict__ part, float* __restrict__ scal_part)
{
    __shared__ __align__(16) float c_lds[BB * ROWS];   // 4 KB  [b][row]
    __shared__ float4 red[2 * BB * 64];                // 32 KB [buf][b][lane]
    int x = blockIdx.x, y = blockIdx.y;
    int t = threadIdx.x;
    int w = t >> 6, l = t & 63;
    const float* Wm; int i0;

    if (y < YINT) {
        i0 = y * ROWS; Wm = Wint;
        #pragma unroll
        for (int bb = 0; bb < 4; ++bb) {
            int b = w * 4 + bb;
            int base = b * NN + i0 + l;
            float acc = 0.f;
            #pragma unroll
            for (int d = 0; d < DD; ++d) {
                float xd = Xbuf[d * BN + base];   // coalesced 256B
                float s  = stp[d * BN + base];
                acc += xd * (1.f + 0.95f * s - 0.3f * xd);
            }
            c_lds[b * ROWS + l] = acc;            // lane-consecutive write
        }
    } else {
        i0 = (y - YINT) * ROWS; Wm = Wff;
        #pragma unroll
        for (int bb = 0; bb < 4; ++bb) {
            int b = w * 4 + bb;
            c_lds[b * ROWS + l] = FF[b * NFF + i0 + l];
        }
    }
    __syncthreads();

    // scal partials (x==0 blocks; all reads coalesced, wave-parallel)
    if (x == 0) {
        #pragma unroll
        for (int bb = 0; bb < 4; ++bb) {
            int b = w * 4 + bb;
            float tv = c_lds[b * ROWS + l];
            float s0, s1;
            if (y < YINT) {
                s0 = tv * xpre_int[b * NN + i0 + l];
                s1 = tv * Xbuf[b * NN + i0 + l];          // Xd0
            } else {
                s0 = tv * xpre_ff[b * NFF + i0 + l];
                s1 = tv * tv;
            }
            #pragma unroll
            for (int o = 32; o; o >>= 1) { s0 += __shfl_xor(s0, o); s1 += __shfl_xor(s1, o); }
            if (l == 0) {
                scal_part[y * 32 + b]      = s0;
                scal_part[y * 32 + 16 + b] = s1;
            }
        }
    }

    int j0 = x * JC + l * 4;
    const float* wp = Wm + (size_t)(i0 + w * WR) * NN + j0;

    float4 acc[BB];
    #pragma unroll
    for (int b = 0; b < BB; ++b) acc[b] = make_float4(0.f, 0.f, 0.f, 0.f);

    float4 buf[8];

#define FMA16(b, base) { \
        float4 cr = *(const float4*)&c_lds[(b) * ROWS + (base)]; \
        acc[b].x += cr.x * wv0.x + cr.y * wv1.x + cr.z * wv2.x + cr.w * wv3.x; \
        acc[b].y += cr.x * wv0.y + cr.y * wv1.y + cr.z * wv2.y + cr.w * wv3.y; \
        acc[b].z += cr.x * wv0.z + cr.y * wv1.z + cr.z * wv2.z + cr.w * wv3.z; \
        acc[b].w += cr.x * wv0.w + cr.y * wv1.w + cr.z * wv2.w + cr.w * wv3.w; }

    // ---- half-pass 1: rows 0..7 of this wave's 16 ----
    #pragma unroll
    for (int r = 0; r < 8; ++r) buf[r] = *(const float4*)(wp + (size_t)r * NN);
    #pragma unroll
    for (int rg = 0; rg < 2; ++rg) {
        float4 wv0 = buf[rg * 4 + 0], wv1 = buf[rg * 4 + 1];
        float4 wv2 = buf[rg * 4 + 2], wv3 = buf[rg * 4 + 3];
        int base = w * WR + rg * 4;
        FMA16(0,  base) FMA16(1,  base) FMA16(2,  base) FMA16(3,  base)
        FMA16(4,  base) FMA16(5,  base) FMA16(6,  base) FMA16(7,  base)
        FMA16(8,  base) FMA16(9,  base) FMA16(10, base) FMA16(11, base)
        FMA16(12, base) FMA16(13, base) FMA16(14, base) FMA16(15, base)
    }

    // ---- half-pass 2: rows 8..15 (reuse buf registers) ----
    #pragma unroll
    for (int r = 0; r < 8; ++r) buf[r] = *(const float4*)(wp + (size_t)(8 + r) * NN);
    #pragma unroll
    for (int rg = 0; rg < 2; ++rg) {
        float4 wv0 = buf[rg * 4 + 0], wv1 = buf[rg * 4 + 1];
        float4 wv2 = buf[rg * 4 + 2], wv3 = buf[rg * 4 + 3];
        int base = w * WR + 8 + rg * 4;
        FMA16(0,  base) FMA16(1,  base) FMA16(2,  base) FMA16(3,  base)
        FMA16(4,  base) FMA16(5,  base) FMA16(6,  base) FMA16(7,  base)
        FMA16(8,  base) FMA16(9,  base) FMA16(10, base) FMA16(11, base)
        FMA16(12, base) FMA16(13, base) FMA16(14, base) FMA16(15, base)
    }
#undef FMA16

    // tree-reduce 4 waves: [b][lane] float4, contiguous b128 ops
    if (w >= 2) {
        float4* rb = &red[(w - 2) * BB * 64];
        #pragma unroll
        for (int b = 0; b < BB; ++b) rb[b * 64 + l] = acc[b];
    }
    __syncthreads();
    if (w < 2) {
        const float4* rb = &red[w * BB * 64];
        #pragma unroll
        for (int b = 0; b < BB; ++b) {
            float4 v = rb[b * 64 + l];
            acc[b].x += v.x; acc[b].y += v.y; acc[b].z += v.z; acc[b].w += v.w;
        }
    }
    __syncthreads();
    if (w == 1) {
        #pragma unroll
        for (int b = 0; b < BB; ++b) red[b * 64 + l] = acc[b];
    }
    __syncthreads();
    if (w == 0) {
        float* pp = part + (size_t)y * BN + j0;
        #pragma unroll
        for (int b = 0; b < BB; ++b) {
            float4 v = red[b * 64 + l];
            acc[b].x += v.x; acc[b].y += v.y; acc[b].z += v.z; acc[b].w += v.w;
            *(float4*)(pp + (size_t)b * NN) = acc[b];
        }
    }
}

// ---------------- Kernel B: X + reduce partials + finalize ----------------
__global__ __launch_bounds__(256) void snn_post(
    const float* __restrict__ V, const float* __restrict__ th,
    const float* __restrict__ xpost,
    const float* __restrict__ part, const float* __restrict__ scal_part,
    float* __restrict__ out_X, float* __restrict__ out_V)
{
    int idx = blockIdx.x * 256 + threadIdx.x;
    int b = idx >> 11;                   // block-uniform
    float c1 = 0.f, c2 = 0.f, c3 = 0.f, c4 = 0.f;
    #pragma unroll
    for (int y = 0; y < YINT; ++y) {
        c1 += scal_part[y * 32 + b];
        c2 += scal_part[y * 32 + 16 + b];
    }
    #pragma unroll
    for (int y = YINT; y < YTOT; ++y) {
        c3 += scal_part[y * 32 + b];
        c4 += scal_part[y * 32 + 16 + b];
    }
    float v = V[idx];
    float x = 1.f / (1.f + expf(-(v - 1.f - th[idx]) * 5.f));
    out_X[idx] = x;
    float s = 0.f;
    #pragma unroll
    for (int y = 0; y < YTOT; ++y) s += part[(size_t)y * BN + idx];
    float c = s + 0.01f * (c1 + c3) * x - 0.012f * (c2 + c4) * xpost[idx];
    out_V[idx] = 0.9f * v * (1.f - x) + c;
}

extern "C" void kernel_launch(void* const* d_in, const int* in_sizes, int n_in,
                              void* d_out, int out_size, void* d_ws, size_t ws_size,
                              hipStream_t stream) {
    const float* FF       = (const float*)d_in[0];
    const float* V        = (const float*)d_in[1];
    const float* th       = (const float*)d_in[2];
    const float* Xbuf     = (const float*)d_in[3];
    const float* stp      = (const float*)d_in[4];
    const float* xpre_int = (const float*)d_in[5];
    const float* xpost    = (const float*)d_in[6];
    const float* xpre_ff  = (const float*)d_in[7];
    const float* Wint     = (const float*)d_in[8];
    const float* Wff      = (const float*)d_in[9];
    float* out = (float*)d_out;
    float* ws  = (float*)d_ws;

    float* part = ws;                    // 40 * 32768 floats (plain stores)
    float* sp   = ws + YTOT * BN;        // 1280 floats (plain stores)

    snn_gemv<<<dim3(NX, YTOT), 256, 0, stream>>>(
        Wint, Wff, Xbuf, stp, FF, xpre_int, xpre_ff, part, sp);

    snn_post<<<BN / 256, 256, 0, stream>>>(
        V, th, xpost, part, sp, out, out + BN);
}